// Round 4
// baseline (319.195 us; speedup 1.0000x reference)
//
#include <hip/hip_runtime.h>
#include <stdint.h>

#define HIDDEN 1024
#define INTER  4096
#define NWORDS 64          // INTER / 64 bit-words per row
#define ROWS   8192        // 4 * 2048
#define MT     8           // rows per GEMM block
#define GBLK   (ROWS / MT) // 1024 gemm blocks
#define GTHR   512         // gemm block threads (8 waves)

typedef unsigned long long u64;

// Packing convention (identical for A and W; popcount(xor) is invariant to
// any fixed bit permutation, only consistency matters):
//   chunk c = elements [256c, 256c+256); lane l loads float4 at 256c+4l;
//   word 4c+j = ballot of component j. After the loop, lane k (=4c+j) holds
//   word k of its row in a register -> one store per lane.

// ---------------------------------------------------------------------------
// Fused pack kernel, one wave per row. 4 waves / 256-thread block.
//  waves [0, 8192):        hs rows -> abits[mblk][k][mi]  (mblk=m>>3, mi=m&7)
//  waves [8192, 8192+1024): W rows  -> wbits[k][h] + wscale[h]=mean|W[h,:]|
// ---------------------------------------------------------------------------
__global__ __launch_bounds__(256)
void pack_kernel(const float* __restrict__ hs, const float* __restrict__ W,
                 u64* __restrict__ abits, u64* __restrict__ wbits,
                 float* __restrict__ wscale) {
    int lane = threadIdx.x & 63;
    int wv   = threadIdx.x >> 6;
    int gw   = blockIdx.x * 4 + wv;
    int l4   = lane & 3;          // which float4 component this lane keeps
    int lc   = lane >> 2;         // which chunk this lane keeps

    if (gw < ROWS) {
        const float4* row = (const float4*)(hs + (size_t)gw * INTER);
        u64 myword = 0;
        #pragma unroll
        for (int c = 0; c < 16; ++c) {
            float4 v = row[c * 64 + lane];
            u64 b0 = __ballot(v.x < 0.0f);
            u64 b1 = __ballot(v.y < 0.0f);
            u64 b2 = __ballot(v.z < 0.0f);
            u64 b3 = __ballot(v.w < 0.0f);
            u64 sel = b0;
            sel = (l4 == 1) ? b1 : sel;
            sel = (l4 == 2) ? b2 : sel;
            sel = (l4 == 3) ? b3 : sel;
            myword = (lc == c) ? sel : myword;
        }
        // transposed store: lane k -> [mblk][k][mi]
        abits[(size_t)(gw >> 3) * NWORDS * MT + (size_t)lane * MT + (gw & 7)] = myword;
    } else {
        int h = gw - ROWS;
        const float4* row = (const float4*)(W + (size_t)h * INTER);
        u64 myword = 0;
        float asum = 0.f;
        #pragma unroll
        for (int c = 0; c < 16; ++c) {
            float4 v = row[c * 64 + lane];
            asum += fabsf(v.x) + fabsf(v.y) + fabsf(v.z) + fabsf(v.w);
            u64 b0 = __ballot(v.x < 0.0f);
            u64 b1 = __ballot(v.y < 0.0f);
            u64 b2 = __ballot(v.z < 0.0f);
            u64 b3 = __ballot(v.w < 0.0f);
            u64 sel = b0;
            sel = (l4 == 1) ? b1 : sel;
            sel = (l4 == 2) ? b2 : sel;
            sel = (l4 == 3) ? b3 : sel;
            myword = (lc == c) ? sel : myword;
        }
        wbits[(size_t)lane * HIDDEN + h] = myword;
        #pragma unroll
        for (int off = 32; off > 0; off >>= 1) asum += __shfl_down(asum, off);
        if (lane == 0) wscale[h] = asum * (1.0f / INTER);
    }
}

// ---------------------------------------------------------------------------
// Binary GEMM + bias + residual + LayerNorm.
// Block = 8 rows x 1024 cols, 512 threads (8 waves); thread t owns cols
// h = 2t, 2t+1. A-words: wave-uniform contiguous 64B per k -> s_load (scalar
// pipe, zero VALU/LDS). dot = INTER - 2*popc(a ^ w).
// ---------------------------------------------------------------------------
__global__ __launch_bounds__(GTHR, 8)
void gemm_ln_kernel(const u64* __restrict__ abits, const u64* __restrict__ wbits,
                    const float* __restrict__ wscale, const float* __restrict__ bias,
                    const float* __restrict__ clipp, const float* __restrict__ input,
                    const float* __restrict__ gamma, const float* __restrict__ beta,
                    float* __restrict__ out) {
    int t  = threadIdx.x;                  // 0..511
    int m0 = blockIdx.x * MT;
    int h0 = t * 2;
    const u64* ablk = abits + (size_t)blockIdx.x * NWORDS * MT;

    int acc[MT][2];
    #pragma unroll
    for (int mi = 0; mi < MT; ++mi) { acc[mi][0] = 0; acc[mi][1] = 0; }

    #pragma unroll 4
    for (int k = 0; k < NWORDS; ++k) {
        ulonglong2 w = *(const ulonglong2*)(wbits + (size_t)k * HIDDEN + h0);
        const u64* ap = ablk + k * MT;     // wave-uniform -> s_load_dwordx16
        #pragma unroll
        for (int mi = 0; mi < MT; ++mi) {
            u64 a  = ap[mi];
            u64 x0 = a ^ w.x;
            u64 x1 = a ^ w.y;
            acc[mi][0] += __popc((uint32_t)x0) + __popc((uint32_t)(x0 >> 32));
            acc[mi][1] += __popc((uint32_t)x1) + __popc((uint32_t)(x1 >> 32));
        }
    }

    // ---- epilogue: bias + residual + LayerNorm ----
    float clip = clipp[0];
    float2 cw = reinterpret_cast<const float2*>(wscale)[t];
    cw.x *= clip; cw.y *= clip;
    float2 bi = reinterpret_cast<const float2*>(bias)[t];
    float2 gm = reinterpret_cast<const float2*>(gamma)[t];
    float2 bt = reinterpret_cast<const float2*>(beta)[t];

    float vals[MT][2];
    #pragma unroll
    for (int mi = 0; mi < MT; ++mi) {
        float2 inp = reinterpret_cast<const float2*>(input + (size_t)(m0 + mi) * HIDDEN)[t];
        vals[mi][0] = fmaf((float)(INTER - 2 * acc[mi][0]), cw.x, bi.x + inp.x);
        vals[mi][1] = fmaf((float)(INTER - 2 * acc[mi][1]), cw.y, bi.y + inp.y);
    }

    __shared__ float red_s[8][MT];
    __shared__ float red_q[8][MT];
    __shared__ float s_mu[MT], s_rs[MT];
    int lane = t & 63, wv = t >> 6;
    #pragma unroll
    for (int mi = 0; mi < MT; ++mi) {
        float s = vals[mi][0] + vals[mi][1];
        float q = vals[mi][0] * vals[mi][0] + vals[mi][1] * vals[mi][1];
        #pragma unroll
        for (int off = 32; off > 0; off >>= 1) {
            s += __shfl_down(s, off);
            q += __shfl_down(q, off);
        }
        if (lane == 0) { red_s[wv][mi] = s; red_q[wv][mi] = q; }
    }
    __syncthreads();
    if (t < MT) {
        float s = 0.f, q = 0.f;
        #pragma unroll
        for (int w = 0; w < 8; ++w) { s += red_s[w][t]; q += red_q[w][t]; }
        float mu  = s * (1.0f / HIDDEN);
        float var = fmaf(-mu, mu, q * (1.0f / HIDDEN));
        s_mu[t] = mu;
        s_rs[t] = rsqrtf(var + 1e-12f);
    }
    __syncthreads();

    #pragma unroll
    for (int mi = 0; mi < MT; ++mi) {
        float mu = s_mu[mi], rs = s_rs[mi];
        float2 o;
        o.x = (vals[mi][0] - mu) * rs * gm.x + bt.x;
        o.y = (vals[mi][1] - mu) * rs * gm.y + bt.y;
        reinterpret_cast<float2*>(out + (size_t)(m0 + mi) * HIDDEN)[t] = o;
    }
}

// ---------------------------------------------------------------------------
extern "C" void kernel_launch(void* const* d_in, const int* in_sizes, int n_in,
                              void* d_out, int out_size, void* d_ws, size_t ws_size,
                              hipStream_t stream) {
    const float* hs    = (const float*)d_in[0];  // [4,2048,4096]
    const float* inp   = (const float*)d_in[1];  // [4,2048,1024]
    const float* W     = (const float*)d_in[2];  // [1024,4096]
    const float* b     = (const float*)d_in[3];  // [1024]
    const float* clip  = (const float*)d_in[4];  // scalar
    const float* gamma = (const float*)d_in[5];  // [1024]
    const float* beta  = (const float*)d_in[6];  // [1024]
    float* out = (float*)d_out;

    u64*   abits  = (u64*)d_ws;                                        // 4 MB
    u64*   wbits  = (u64*)((char*)d_ws + (size_t)ROWS * NWORDS * 8);   // 512 KB
    float* wscale = (float*)((char*)d_ws + (size_t)ROWS * NWORDS * 8
                                         + (size_t)NWORDS * HIDDEN * 8); // 4 KB

    // 8192 hs waves + 1024 W waves, 4 waves per block
    pack_kernel<<<(ROWS + HIDDEN) / 4, 256, 0, stream>>>(hs, W, abits, wbits, wscale);
    gemm_ln_kernel<<<GBLK, GTHR, 0, stream>>>(abits, wbits, wscale, b, clip,
                                              inp, gamma, beta, out);
}